// Round 11
// baseline (88.425 us; speedup 1.0000x reference)
//
#include <hip/hip_runtime.h>

typedef float v2f __attribute__((ext_vector_type(2)));
typedef float v4f __attribute__((ext_vector_type(4)));

constexpr int IN_D = 18, W_HID = 10, N_HID = 19;
constexpr float SLOPE = 0.1f;

// LDS layout in float2 PAIRS, each pair = (w, w) duplicated:
//   hidden: l*120 + j*12 + k     (k=0..9 weights, 10 bias, 11 pad)
//   W0:     2280 + j*20 + c      (c=0..17 weights, 18 bias, 19 pad)
//   Wf:     2480 + k             (k=0..9 weights, 10 bias, 11 pad)
constexpr int P_H = 0, P_L0 = 2280, P_F = 2480, N_PAIRS = 2492;

__device__ __forceinline__ v2f pk_fma(v2f acc, v2f x, v2f w) {
    asm("v_pk_fma_f32 %0, %1, %2, %0" : "+v"(acc) : "v"(x), "v"(w));
    return acc;
}
// NOTE: v_pk_max_f32 does NOT exist on gfx950 (R10 compile fail).
// lrelu = v_pk_mul_f32 + 2x scalar v_max_f32.
__device__ __forceinline__ v2f pk_lrelu(v2f x, v2f slope2) {
    v2f y;
    asm("v_pk_mul_f32 %0, %1, %2" : "=v"(y) : "v"(x), "v"(slope2));
    v2f r;
    r[0] = fmaxf(x[0], y[0]);
    r[1] = fmaxf(x[1], y[1]);
    return r;
}
#define SHUF(q, a, b) __builtin_shufflevector((q), (q), (a), (b))

// 10->10 layer; per row: 6x ds_read_b128 (uniform addr -> broadcast), 10 pk_fma, bias = loaded pair.
__device__ __forceinline__ void layer10_lds(const v2f* __restrict__ in, v2f* __restrict__ outv,
                                            const float2* __restrict__ lrow, v2f slope2) {
    #pragma unroll
    for (int j = 0; j < W_HID; ++j) {
        const v4f* rp = reinterpret_cast<const v4f*>(lrow + j * 12);
        v4f q0 = rp[0], q1 = rp[1], q2 = rp[2], q3 = rp[3], q4 = rp[4], q5 = rp[5];
        v2f acc = SHUF(q5, 0, 1);                 // bias pair
        acc = pk_fma(acc, in[0], SHUF(q0, 0, 1));
        acc = pk_fma(acc, in[1], SHUF(q0, 2, 3));
        acc = pk_fma(acc, in[2], SHUF(q1, 0, 1));
        acc = pk_fma(acc, in[3], SHUF(q1, 2, 3));
        acc = pk_fma(acc, in[4], SHUF(q2, 0, 1));
        acc = pk_fma(acc, in[5], SHUF(q2, 2, 3));
        acc = pk_fma(acc, in[6], SHUF(q3, 0, 1));
        acc = pk_fma(acc, in[7], SHUF(q3, 2, 3));
        acc = pk_fma(acc, in[8], SHUF(q4, 0, 1));
        acc = pk_fma(acc, in[9], SHUF(q4, 2, 3));
        outv[j] = pk_lrelu(acc, slope2);
    }
}

__global__ __launch_bounds__(256, 4) void critic_pk_ldsdup(
    const float* __restrict__ state, const float* __restrict__ action,
    const float* __restrict__ W0, const float* __restrict__ b0,
    const float* __restrict__ Ws, const float* __restrict__ bs,
    const float* __restrict__ Wf, const float* __restrict__ bf,
    float* __restrict__ out, int B)
{
    __shared__ float2 lw[N_PAIRS];
    const int tid = threadIdx.x;

    // ---- stage duplicated weight pairs (once per block) ----
    for (int idx = tid; idx < 1900; idx += 256) {
        int l = idx / 100, rem = idx % 100, r = rem / 10, c = rem % 10;
        float w = Ws[idx]; lw[P_H + l * 120 + r * 12 + c] = make_float2(w, w);
    }
    for (int idx = tid; idx < 190; idx += 256) {
        int l = idx / 10, r = idx % 10;
        float w = bs[idx]; lw[P_H + l * 120 + r * 12 + 10] = make_float2(w, w);
    }
    for (int idx = tid; idx < 180; idx += 256) {
        int r = idx / 18, c = idx % 18;
        float w = W0[idx]; lw[P_L0 + r * 20 + c] = make_float2(w, w);
    }
    if (tid < 10)  { float w = b0[tid]; lw[P_L0 + tid * 20 + 18] = make_float2(w, w); }
    if (tid >= 32 && tid < 42) { float w = Wf[tid - 32]; lw[P_F + (tid - 32)] = make_float2(w, w); }
    if (tid == 64) { float w = bf[0]; lw[P_F + 10] = make_float2(w, w); }
    __syncthreads();

    const int t = blockIdx.x * blockDim.x + tid;
    if (t * 2 >= B) return;

    const v2f slope2 = {SLOPE, SLOPE};

    // ---- 2 state rows (96 B) + 2 action rows (48 B), all float4 ----
    float Sf[24];
    {
        const float4* s4 = reinterpret_cast<const float4*>(state) + (size_t)t * 6;
        #pragma unroll
        for (int r = 0; r < 6; ++r) {
            float4 v = s4[r];
            Sf[4*r] = v.x; Sf[4*r+1] = v.y; Sf[4*r+2] = v.z; Sf[4*r+3] = v.w;
        }
    }
    float Af[12];
    {
        const float4* a4 = reinterpret_cast<const float4*>(action) + (size_t)t * 3;
        #pragma unroll
        for (int r = 0; r < 3; ++r) {
            float4 v = a4[r];
            Af[4*r] = v.x; Af[4*r+1] = v.y; Af[4*r+2] = v.z; Af[4*r+3] = v.w;
        }
    }
    v2f x[IN_D];
    #pragma unroll
    for (int k = 0; k < 12; ++k) { v2f v; v[0] = Sf[k]; v[1] = Sf[12 + k]; x[k] = v; }
    #pragma unroll
    for (int k = 0; k < 6; ++k)  { v2f v; v[0] = Af[k]; v[1] = Af[6 + k];  x[12 + k] = v; }

    // ---- layer 0: 18 -> 10 (rows of 20 pairs -> 10x b128) ----
    v2f h[W_HID], g[W_HID];
    #pragma unroll
    for (int j = 0; j < W_HID; ++j) {
        const v4f* rp = reinterpret_cast<const v4f*>(lw + P_L0 + j * 20);
        v4f q0 = rp[0], q1 = rp[1], q2 = rp[2], q3 = rp[3], q4 = rp[4];
        v4f q5 = rp[5], q6 = rp[6], q7 = rp[7], q8 = rp[8], q9 = rp[9];
        v2f acc = SHUF(q9, 0, 1);                 // b0[j] pair (pair 18)
        acc = pk_fma(acc, x[0],  SHUF(q0, 0, 1));
        acc = pk_fma(acc, x[1],  SHUF(q0, 2, 3));
        acc = pk_fma(acc, x[2],  SHUF(q1, 0, 1));
        acc = pk_fma(acc, x[3],  SHUF(q1, 2, 3));
        acc = pk_fma(acc, x[4],  SHUF(q2, 0, 1));
        acc = pk_fma(acc, x[5],  SHUF(q2, 2, 3));
        acc = pk_fma(acc, x[6],  SHUF(q3, 0, 1));
        acc = pk_fma(acc, x[7],  SHUF(q3, 2, 3));
        acc = pk_fma(acc, x[8],  SHUF(q4, 0, 1));
        acc = pk_fma(acc, x[9],  SHUF(q4, 2, 3));
        acc = pk_fma(acc, x[10], SHUF(q5, 0, 1));
        acc = pk_fma(acc, x[11], SHUF(q5, 2, 3));
        acc = pk_fma(acc, x[12], SHUF(q6, 0, 1));
        acc = pk_fma(acc, x[13], SHUF(q6, 2, 3));
        acc = pk_fma(acc, x[14], SHUF(q7, 0, 1));
        acc = pk_fma(acc, x[15], SHUF(q7, 2, 3));
        acc = pk_fma(acc, x[16], SHUF(q8, 0, 1));
        acc = pk_fma(acc, x[17], SHUF(q8, 2, 3));
        h[j] = pk_lrelu(acc, slope2);
    }

    // ---- hidden layers: rolled, 2 per iteration (ping-pong h->g->h) ----
    const float2* lb = lw + P_H;
    #pragma unroll 1
    for (int it = 0; it < (N_HID - 1) / 2; ++it) {
        layer10_lds(h, g, lb,       slope2);
        layer10_lds(g, h, lb + 120, slope2);
        lb += 240;
    }
    layer10_lds(h, g, lb, slope2);   // hidden layer 18

    // ---- final layer: 10 -> 1 ----
    {
        const v4f* rp = reinterpret_cast<const v4f*>(lw + P_F);
        v4f q0 = rp[0], q1 = rp[1], q2 = rp[2], q3 = rp[3], q4 = rp[4], q5 = rp[5];
        v2f acc = SHUF(q5, 0, 1);                 // bf pair
        acc = pk_fma(acc, g[0], SHUF(q0, 0, 1));
        acc = pk_fma(acc, g[1], SHUF(q0, 2, 3));
        acc = pk_fma(acc, g[2], SHUF(q1, 0, 1));
        acc = pk_fma(acc, g[3], SHUF(q1, 2, 3));
        acc = pk_fma(acc, g[4], SHUF(q2, 0, 1));
        acc = pk_fma(acc, g[5], SHUF(q2, 2, 3));
        acc = pk_fma(acc, g[6], SHUF(q3, 0, 1));
        acc = pk_fma(acc, g[7], SHUF(q3, 2, 3));
        acc = pk_fma(acc, g[8], SHUF(q4, 0, 1));
        acc = pk_fma(acc, g[9], SHUF(q4, 2, 3));
        acc = pk_lrelu(acc, slope2);
        float2 o; o.x = acc[0]; o.y = acc[1];
        reinterpret_cast<float2*>(out)[t] = o;
    }
}

extern "C" void kernel_launch(void* const* d_in, const int* in_sizes, int n_in,
                              void* d_out, int out_size, void* d_ws, size_t ws_size,
                              hipStream_t stream) {
    const float* state  = (const float*)d_in[0];
    const float* action = (const float*)d_in[1];
    const float* W0     = (const float*)d_in[2];
    const float* b0     = (const float*)d_in[3];
    const float* Ws     = (const float*)d_in[4];
    const float* bs     = (const float*)d_in[5];
    const float* Wf     = (const float*)d_in[6];
    const float* bf     = (const float*)d_in[7];
    float* out = (float*)d_out;

    const int B = out_size;                  // [1, B] flat; B = 1048576 (even)
    const int nthreads = B / 2;              // 2 samples per thread
    const int block = 256;
    const int grid = (nthreads + block - 1) / block;
    critic_pk_ldsdup<<<grid, block, 0, stream>>>(state, action, W0, b0, Ws, bs, Wf, bf, out, B);
}